// Round 1
// 12160.513 us; speedup vs baseline: 2.5628x; 2.5628x over previous
//
#include <hip/hip_runtime.h>
#include <math.h>

#define L_  12
#define B_  2
#define T_  448
#define D_  768
#define H_  12
#define HD_ 64
#define V_  51865
#define NC_ 448
#define CT_ 1500
#define FF_ 3072
#define M_  (B_*T_)   // 896 rows

typedef __attribute__((ext_vector_type(4))) float f32x4;
typedef __attribute__((ext_vector_type(8))) short bf16x8;
typedef __attribute__((ext_vector_type(4))) unsigned short u16x4;
typedef __attribute__((ext_vector_type(8))) unsigned short u16x8;

__device__ __forceinline__ unsigned short f2bf(float f) {
    unsigned u = __float_as_uint(f);
    u += 0x7FFFu + ((u >> 16) & 1u);      // round-to-nearest-even
    return (unsigned short)(u >> 16);
}
__device__ __forceinline__ float bf2f(unsigned short h) {
    return __uint_as_float(((unsigned)h) << 16);
}
__device__ __forceinline__ f32x4 mfma_bf16(bf16x8 a, bf16x8 b, f32x4 c) {
    return __builtin_amdgcn_mfma_f32_16x16x32_bf16(a, b, c, 0, 0, 0);
}

// ---------------- embedding ----------------
__global__ void embed_k(const int* __restrict__ tokens, const float* __restrict__ tok_emb,
                        const float* __restrict__ pos_emb, float* __restrict__ x) {
    int idx = blockIdx.x * 256 + threadIdx.x;
    if (idx >= M_ * D_) return;
    int row = idx / D_, d = idx % D_;
    int t = row % T_;
    int tok = tokens[row];
    x[idx] = tok_emb[(size_t)tok * D_ + d] + pos_emb[(size_t)t * D_ + d];
}

// ---------------- layernorm (block per row, 256 thr) ----------------
__global__ __launch_bounds__(256) void ln_k(const float* __restrict__ x, const float* __restrict__ g,
                                            const float* __restrict__ b, float* __restrict__ out) {
    int row = blockIdx.x;
    const float* xr = x + (size_t)row * D_;
    float s = 0.f, ss = 0.f;
    for (int i = threadIdx.x; i < D_; i += 256) { float v = xr[i]; s += v; ss += v * v; }
    for (int o = 32; o > 0; o >>= 1) { s += __shfl_down(s, o); ss += __shfl_down(ss, o); }
    __shared__ float red0[4], red1[4];
    __shared__ float bm, binv;
    int wid = threadIdx.x >> 6, lid = threadIdx.x & 63;
    if (lid == 0) { red0[wid] = s; red1[wid] = ss; }
    __syncthreads();
    if (threadIdx.x == 0) {
        float S = 0.f, SS = 0.f;
        for (int i = 0; i < 4; i++) { S += red0[i]; SS += red1[i]; }
        float m = S / D_;
        float var = SS / D_ - m * m;
        bm = m; binv = rsqrtf(var + 1e-5f);
    }
    __syncthreads();
    float m = bm, inv = binv;
    float* orow = out + (size_t)row * D_;
    for (int i = threadIdx.x; i < D_; i += 256)
        orow[i] = (xr[i] - m) * inv * g[i] + b[i];
}

// ---------------- bf16x3 MFMA GEMM core ----------------
// C(MxN) = A(MxK) @ B  [+bias] [+resid], fp32 in/out.
// TRANS==0: B is KxN row-major (NN).  TRANS==1: B is NxK row-major (NT).
// Tile 64x64, K-step 64, 256 threads = 4 waves (2x2), each wave 32x32 via
// 2x2 fragments of v_mfma_f32_16x16x32_bf16.
// LDS tiles stored [row][k] as bf16 hi/lo with XOR swizzle:
//   byte = row*128 + ((kgroup ^ (row&7))<<4)   (kgroup = 16B group of 8 bf16)
// A-frag: lane holds A[row=lane&15][k=(lane>>4)*8+i]; B-frag same with row=col.
// C/D: elem j -> row=(lane>>4)*4+j, col=lane&15  [m89/m91-verified layout]
// Requires: M % 64 == 0, K % 64 == 0 (true for all call sites; N may be ragged).
template<int TRANS>
__device__ __forceinline__ void gemm_dev(const float* __restrict__ A, const float* __restrict__ B,
                                         const float* __restrict__ bias, const float* __restrict__ resid,
                                         float* __restrict__ C, int M, int N, int K, int m0, int n0) {
    __shared__ unsigned short AsH[64 * 64], AsL[64 * 64], BsH[64 * 64], BsL[64 * 64];
    const int tid  = threadIdx.x;
    const int lane = tid & 63;
    const int wid  = tid >> 6;
    const int wm   = wid >> 1, wn = wid & 1;

    f32x4 acc[2][2] = {};

    const int arow = tid >> 2;     // 0..63 : tile row (A) / tile col (B-NT)
    const int aseg = tid & 3;      // which 16-float k-segment
    const int bn4  = tid & 15;     // B-NN: n quad
    const int bku  = tid >> 4;     // B-NN: k quad (0..15)

    for (int kt = 0; kt < K; kt += 64) {
        // ---- stage A: rows m0..m0+63, k kt..kt+63 ----
        {
            const float* ap = A + (size_t)(m0 + arow) * K + kt + aseg * 16;
            #pragma unroll
            for (int gg = 0; gg < 2; gg++) {
                f32x4 v0 = *(const f32x4*)(ap + gg * 8);
                f32x4 v1 = *(const f32x4*)(ap + gg * 8 + 4);
                u16x8 h8, l8;
                #pragma unroll
                for (int j = 0; j < 4; j++) {
                    unsigned short h0 = f2bf(v0[j]);
                    h8[j] = h0;       l8[j] = f2bf(v0[j] - bf2f(h0));
                    unsigned short h1 = f2bf(v1[j]);
                    h8[4 + j] = h1;   l8[4 + j] = f2bf(v1[j] - bf2f(h1));
                }
                int g  = aseg * 2 + gg;
                int si = arow * 64 + ((g ^ (arow & 7)) << 3);
                *(u16x8*)(AsH + si) = h8;
                *(u16x8*)(AsL + si) = l8;
            }
        }
        // ---- stage B ----
        if (TRANS == 0) {
            // B[k][n]: read 4x4 sub-tile coalesced along n, transpose to LDS [n][k]
            const float* bp = B + (size_t)(kt + bku * 4) * N + n0 + bn4 * 4;
            f32x4 r0 = *(const f32x4*)(bp);
            f32x4 r1 = *(const f32x4*)(bp + (size_t)N);
            f32x4 r2 = *(const f32x4*)(bp + 2 * (size_t)N);
            f32x4 r3 = *(const f32x4*)(bp + 3 * (size_t)N);
            #pragma unroll
            for (int c = 0; c < 4; c++) {
                int nl = bn4 * 4 + c;
                float x0 = r0[c], x1 = r1[c], x2 = r2[c], x3 = r3[c];
                u16x4 h4, l4;
                unsigned short h;
                h = f2bf(x0); h4[0] = h; l4[0] = f2bf(x0 - bf2f(h));
                h = f2bf(x1); h4[1] = h; l4[1] = f2bf(x1 - bf2f(h));
                h = f2bf(x2); h4[2] = h; l4[2] = f2bf(x2 - bf2f(h));
                h = f2bf(x3); h4[3] = h; l4[3] = f2bf(x3 - bf2f(h));
                int si = nl * 64 + (((bku >> 1) ^ (nl & 7)) << 3) + (bku & 1) * 4;
                *(u16x4*)(BsH + si) = h4;
                *(u16x4*)(BsL + si) = l4;
            }
        } else {
            // B[n][k]: same pattern as A staging, rows are n (guard ragged N edge)
            int gn = n0 + arow;
            bool ok = (gn < N);
            const float* bp = B + (size_t)gn * K + kt + aseg * 16;
            #pragma unroll
            for (int gg = 0; gg < 2; gg++) {
                f32x4 v0 = {0.f, 0.f, 0.f, 0.f}, v1 = {0.f, 0.f, 0.f, 0.f};
                if (ok) {
                    v0 = *(const f32x4*)(bp + gg * 8);
                    v1 = *(const f32x4*)(bp + gg * 8 + 4);
                }
                u16x8 h8, l8;
                #pragma unroll
                for (int j = 0; j < 4; j++) {
                    unsigned short h0 = f2bf(v0[j]);
                    h8[j] = h0;       l8[j] = f2bf(v0[j] - bf2f(h0));
                    unsigned short h1 = f2bf(v1[j]);
                    h8[4 + j] = h1;   l8[4 + j] = f2bf(v1[j] - bf2f(h1));
                }
                int g  = aseg * 2 + gg;
                int si = arow * 64 + ((g ^ (arow & 7)) << 3);
                *(u16x8*)(BsH + si) = h8;
                *(u16x8*)(BsL + si) = l8;
            }
        }
        __syncthreads();

        // ---- compute: 2 k-steps of 32, 2x2 fragments, 3 MFMAs each (hi*hi, hi*lo, lo*hi) ----
        #pragma unroll
        for (int ks = 0; ks < 2; ks++) {
            bf16x8 aH[2], aL[2], bH[2], bL[2];
            #pragma unroll
            for (int f = 0; f < 2; f++) {
                int g  = ks * 4 + (lane >> 4);
                int r  = wm * 32 + f * 16 + (lane & 15);
                int si = r * 64 + ((g ^ (r & 7)) << 3);
                aH[f] = *(const bf16x8*)(AsH + si);
                aL[f] = *(const bf16x8*)(AsL + si);
                int cc = wn * 32 + f * 16 + (lane & 15);
                int sj = cc * 64 + ((g ^ (cc & 7)) << 3);
                bH[f] = *(const bf16x8*)(BsH + sj);
                bL[f] = *(const bf16x8*)(BsL + sj);
            }
            #pragma unroll
            for (int fm = 0; fm < 2; fm++)
                #pragma unroll
                for (int fn = 0; fn < 2; fn++) {
                    acc[fm][fn] = mfma_bf16(aH[fm], bH[fn], acc[fm][fn]);
                    acc[fm][fn] = mfma_bf16(aH[fm], bL[fn], acc[fm][fn]);
                    acc[fm][fn] = mfma_bf16(aL[fm], bH[fn], acc[fm][fn]);
                }
        }
        __syncthreads();
    }

    // ---- epilogue ----
    #pragma unroll
    for (int fm = 0; fm < 2; fm++) {
        #pragma unroll
        for (int fn = 0; fn < 2; fn++) {
            int gn = n0 + wn * 32 + fn * 16 + (lane & 15);
            if (gn >= N) continue;
            int gm0 = m0 + wm * 32 + fm * 16 + ((lane >> 4) << 2);
            float badd = bias ? bias[gn] : 0.f;
            #pragma unroll
            for (int j = 0; j < 4; j++) {
                int gm = gm0 + j;
                float v = acc[fm][fn][j] + badd;
                if (resid) v += resid[(size_t)gm * N + gn];
                C[(size_t)gm * N + gn] = v;
            }
        }
    }
}

__global__ __launch_bounds__(256) void gemm_nn_mfma_k(const float* __restrict__ A, const float* __restrict__ B,
                                                      const float* __restrict__ bias, const float* __restrict__ resid,
                                                      float* __restrict__ C, int M, int N, int K) {
    gemm_dev<0>(A, B, bias, resid, C, M, N, K, blockIdx.y * 64, blockIdx.x * 64);
}

__global__ __launch_bounds__(256) void gemm_nt_mfma_k(const float* __restrict__ A, const float* __restrict__ Bt,
                                                      float* __restrict__ C, int M, int N, int K) {
    gemm_dev<1>(A, Bt, nullptr, nullptr, C, M, N, K, blockIdx.y * 64, blockIdx.x * 64);
}

// fused Q/K/V projection: grid.x = 3*(D_/64); per-block select of weight/bias/output
__global__ __launch_bounds__(256) void gemm_qkv_k(const float* __restrict__ h,
                                                  const float* __restrict__ Wq, const float* __restrict__ Wk,
                                                  const float* __restrict__ Wv,
                                                  const float* __restrict__ bq, const float* __restrict__ bv,
                                                  float* __restrict__ q, float* __restrict__ kl, float* __restrict__ vl) {
    int which = blockIdx.x / (D_ / 64);
    int nb    = blockIdx.x % (D_ / 64);
    const float* Bm   = (which == 0) ? Wq : (which == 1) ? Wk : Wv;
    const float* bias = (which == 0) ? bq : (which == 2) ? bv : nullptr;
    float*       Cm   = (which == 0) ? q  : (which == 1) ? kl : vl;
    gemm_dev<0>(h, Bm, bias, nullptr, Cm, M_, D_, D_, blockIdx.y * 64, nb * 64);
}

// ---------------- attention scores: S[bh,i,j] = 0.125 * q_h(i)·k_h(j)  (+causal mask) ----------------
__global__ __launch_bounds__(256) void attn_scores_k(const float* __restrict__ q, const float* __restrict__ k,
                                                     float* __restrict__ S, int Tq, int Tk, int causal) {
    int bh = blockIdx.z;
    int b = bh / H_, h = bh % H_;
    int i0 = blockIdx.y * 16, j0 = blockIdx.x * 16;
    __shared__ float Qs[16][HD_ + 1], Ks[16][HD_ + 1];
    int tid = threadIdx.x;
    for (int idx = tid; idx < 16 * HD_; idx += 256) {
        int r = idx >> 6, d = idx & 63;
        int gi = i0 + r;
        Qs[r][d] = (gi < Tq) ? q[((size_t)(b * Tq + gi)) * D_ + h * HD_ + d] : 0.f;
        int gj = j0 + r;
        Ks[r][d] = (gj < Tk) ? k[((size_t)(b * Tk + gj)) * D_ + h * HD_ + d] : 0.f;
    }
    __syncthreads();
    int tx = tid & 15, ty = tid >> 4;
    int gi = i0 + ty, gj = j0 + tx;
    if (gi >= Tq || gj >= Tk) return;
    float acc = 0.f;
    #pragma unroll
    for (int d = 0; d < HD_; d++) acc += Qs[ty][d] * Ks[tx][d];
    float val = acc * 0.125f;   // hd^-0.25 applied to both q and k -> 64^-0.5
    if (causal && gj > gi) val = -INFINITY;
    S[((size_t)bh * Tq + gi) * Tk + gj] = val;
}

// ---------------- row softmax ----------------
__global__ __launch_bounds__(256) void softmax_k(float* __restrict__ S, int ncols) {
    size_t row = blockIdx.x;
    float* r = S + row * (size_t)ncols;
    float mx = -INFINITY;
    for (int i = threadIdx.x; i < ncols; i += 256) mx = fmaxf(mx, r[i]);
    for (int o = 32; o > 0; o >>= 1) mx = fmaxf(mx, __shfl_down(mx, o));
    __shared__ float red[4];
    __shared__ float bmax, bsum;
    int wid = threadIdx.x >> 6, lid = threadIdx.x & 63;
    if (lid == 0) red[wid] = mx;
    __syncthreads();
    if (threadIdx.x == 0) {
        float m = -INFINITY;
        for (int i = 0; i < 4; i++) m = fmaxf(m, red[i]);
        bmax = m;
    }
    __syncthreads();
    mx = bmax;
    float s = 0.f;
    for (int i = threadIdx.x; i < ncols; i += 256) { float e = __expf(r[i] - mx); r[i] = e; s += e; }
    for (int o = 32; o > 0; o >>= 1) s += __shfl_down(s, o);
    if (lid == 0) red[wid] = s;
    __syncthreads();
    if (threadIdx.x == 0) {
        float t = 0.f;
        for (int i = 0; i < 4; i++) t += red[i];
        bsum = t;
    }
    __syncthreads();
    float inv = 1.f / bsum;
    for (int i = threadIdx.x; i < ncols; i += 256) r[i] *= inv;
}

// ---------------- attn output: out[b,i,h,:] = sum_j S[bh,i,j] * v[b,j,h,:] ----------------
__global__ __launch_bounds__(256) void attn_av_k(const float* __restrict__ S, const float* __restrict__ v,
                                                 float* __restrict__ out, int Tq, int Tk) {
    int tid = threadIdx.x;
    int d = tid & 63, r = tid >> 6;      // 4 query rows per block
    int i = blockIdx.x * 4 + r;
    int bh = blockIdx.y;
    int b = bh / H_, h = bh % H_;
    if (i >= Tq) return;
    const float* srow = S + ((size_t)bh * Tq + i) * Tk;
    const float* vcol = v + (size_t)b * Tk * D_ + h * HD_ + d;
    float acc = 0.f;
    #pragma unroll 4
    for (int j = 0; j < Tk; j++) acc += srow[j] * vcol[(size_t)j * D_];
    out[((size_t)(b * Tq + i)) * D_ + h * HD_ + d] = acc;
}

// ---------------- exact gelu ----------------
__global__ void gelu_k(float* __restrict__ x, int n) {
    int i = blockIdx.x * 256 + threadIdx.x;
    if (i < n) { float v = x[i]; x[i] = 0.5f * v * (1.f + erff(v * 0.70710678118f)); }
}

extern "C" void kernel_launch(void* const* d_in, const int* in_sizes, int n_in,
                              void* d_out, int out_size, void* d_ws, size_t ws_size,
                              hipStream_t stream) {
    const int*   tokens     = (const int*)d_in[0];
    const float* cross_k    = (const float*)d_in[3];
    const float* cross_v    = (const float*)d_in[4];
    const float* tok_emb    = (const float*)d_in[6];
    const float* pos_emb    = (const float*)d_in[7];
    const float* attn_ln_g  = (const float*)d_in[9];
    const float* attn_ln_b  = (const float*)d_in[10];
    const float* Wq         = (const float*)d_in[11];
    const float* bq         = (const float*)d_in[12];
    const float* Wk         = (const float*)d_in[13];
    const float* Wv         = (const float*)d_in[14];
    const float* bv         = (const float*)d_in[15];
    const float* Wo         = (const float*)d_in[16];
    const float* bo         = (const float*)d_in[17];
    const float* xattn_ln_g = (const float*)d_in[18];
    const float* xattn_ln_b = (const float*)d_in[19];
    const float* xWq        = (const float*)d_in[20];
    const float* xbq        = (const float*)d_in[21];
    const float* xWo        = (const float*)d_in[22];
    const float* xbo        = (const float*)d_in[23];
    const float* mlp_ln_g   = (const float*)d_in[24];
    const float* mlp_ln_b   = (const float*)d_in[25];
    const float* W1         = (const float*)d_in[26];
    const float* b1         = (const float*)d_in[27];
    const float* W2         = (const float*)d_in[28];
    const float* b2         = (const float*)d_in[29];
    const float* ln_g       = (const float*)d_in[30];
    const float* ln_b       = (const float*)d_in[31];

    float* outp   = (float*)d_out;
    float* logits = outp;                                  // (B,T,V)
    float* kcache = outp + (size_t)B_ * T_ * V_;           // (L,B,NC,D) — fully overwritten (offset=0, NC==T)
    float* vcache = kcache + (size_t)L_ * B_ * NC_ * D_;   // (L,B,NC,D)

    float* ws     = (float*)d_ws;
    float* x      = ws;                       // (M, D)
    float* h      = x + (size_t)M_ * D_;      // (M, D)
    float* q      = h + (size_t)M_ * D_;      // (M, D)
    float* attn   = q + (size_t)M_ * D_;      // (M, D)
    float* mlp    = attn + (size_t)M_ * D_;   // (M, FF)
    float* scores = mlp + (size_t)M_ * FF_;   // (B*H, T, CT) max

    embed_k<<<(M_ * D_ + 255) / 256, 256, 0, stream>>>(tokens, tok_emb, pos_emb, x);

    dim3 gD(D_ / 64, M_ / 64);            // 12 x 14   768-col GEMMs
    dim3 gQKV(3 * D_ / 64, M_ / 64);      // 36 x 14   fused qkv
    dim3 gF(FF_ / 64, M_ / 64);           // 48 x 14   3072-col GEMM
    dim3 gV((V_ + 63) / 64, M_ / 64);     // 811 x 14  logits
    dim3 gsS(T_ / 16, T_ / 16, B_ * H_);  // self scores
    dim3 gsC((CT_ + 15) / 16, T_ / 16, B_ * H_);
    dim3 gav(T_ / 4, B_ * H_);

    for (int l = 0; l < L_; l++) {
        const size_t wofs = (size_t)l * D_ * D_;
        float* kl = kcache + (size_t)l * B_ * NC_ * D_;
        float* vl = vcache + (size_t)l * B_ * NC_ * D_;

        // ---- self attention ----
        ln_k<<<M_, 256, 0, stream>>>(x, attn_ln_g + l * D_, attn_ln_b + l * D_, h);
        gemm_qkv_k<<<gQKV, 256, 0, stream>>>(h, Wq + wofs, Wk + wofs, Wv + wofs,
                                             bq + l * D_, bv + l * D_, q, kl, vl);
        attn_scores_k<<<gsS, 256, 0, stream>>>(q, kl, scores, T_, T_, 1);
        softmax_k<<<B_ * H_ * T_, 256, 0, stream>>>(scores, T_);
        attn_av_k<<<gav, 256, 0, stream>>>(scores, vl, attn, T_, T_);
        gemm_nn_mfma_k<<<gD, 256, 0, stream>>>(attn, Wo + wofs, bo + l * D_, x, x, M_, D_, D_);

        // ---- cross attention ----
        ln_k<<<M_, 256, 0, stream>>>(x, xattn_ln_g + l * D_, xattn_ln_b + l * D_, h);
        gemm_nn_mfma_k<<<gD, 256, 0, stream>>>(h, xWq + wofs, xbq + l * D_, nullptr, q, M_, D_, D_);
        attn_scores_k<<<gsC, 256, 0, stream>>>(q, cross_k + (size_t)l * B_ * CT_ * D_, scores, T_, CT_, 0);
        softmax_k<<<B_ * H_ * T_, 256, 0, stream>>>(scores, CT_);
        attn_av_k<<<gav, 256, 0, stream>>>(scores, cross_v + (size_t)l * B_ * CT_ * D_, attn, T_, CT_);
        gemm_nn_mfma_k<<<gD, 256, 0, stream>>>(attn, xWo + wofs, xbo + l * D_, x, x, M_, D_, D_);

        // ---- mlp ----
        ln_k<<<M_, 256, 0, stream>>>(x, mlp_ln_g + l * D_, mlp_ln_b + l * D_, h);
        gemm_nn_mfma_k<<<gF, 256, 0, stream>>>(h, W1 + (size_t)l * D_ * FF_, b1 + l * FF_, nullptr, mlp, M_, FF_, D_);
        gelu_k<<<(M_ * FF_ + 255) / 256, 256, 0, stream>>>(mlp, M_ * FF_);
        gemm_nn_mfma_k<<<gD, 256, 0, stream>>>(mlp, W2 + (size_t)l * FF_ * D_, b2 + l * D_, x, x, M_, D_, FF_);
    }

    // ---- final LN + logits vs token_embedding^T ----
    ln_k<<<M_, 256, 0, stream>>>(x, ln_g, ln_b, h);
    gemm_nt_mfma_k<<<gV, 256, 0, stream>>>(h, tok_emb, logits, M_, V_, D_);
}